// Round 5
// baseline (223.470 us; speedup 1.0000x reference)
//
#include <hip/hip_runtime.h>
#include <hip/hip_cooperative_groups.h>
#include <math.h>

namespace cg = cooperative_groups;

#define E     128
#define NEXP  8
#define HDIM  512
#define NCLS  1000
#define NB    128
#define EPS   1e-5f

// ---- workspace layout (floats) ----
#define WS_A   0      // a[2][128]
#define WS_H   256    // h[2][128]
#define WS_MH  512    // mh[2][512]
#define WS_MP  1536   // mp[16][128]  (block b<16 -> slot b; kk = b>>3, jc = b&7)

__device__ __forceinline__ float wave_red64(float v) {
    for (int off = 32; off > 0; off >>= 1) v += __shfl_down(v, off, 64);
    return v;
}

// One cooperative kernel, 64 blocks x 256 threads, 4 grid syncs.
__global__ __launch_bounds__(256) void vitmoe_coop(
    const float* __restrict__ cls_token, const float* __restrict__ pos_embed,
    const float* __restrict__ router_w,  const float* __restrict__ router_b,
    const float* __restrict__ ln1_g,     const float* __restrict__ ln1_b,
    const float* __restrict__ wv,        const float* __restrict__ bv,
    const float* __restrict__ wo,        const float* __restrict__ bo,
    const float* __restrict__ ln2_g,     const float* __restrict__ ln2_b,
    const float* __restrict__ w1,        const float* __restrict__ b1,
    const float* __restrict__ w2,        const float* __restrict__ b2,
    const float* __restrict__ norm_g,    const float* __restrict__ norm_b,
    const float* __restrict__ head_w,    const float* __restrict__ head_b,
    float* __restrict__ ws,              float* __restrict__ out)
{
    cg::grid_group grid = cg::this_grid();
    __shared__ float t0s[E], yS[2][E], red[256], lgs[NEXP], hnS[E], part[256], mhs[64], lgq[4], zS[E];
    __shared__ int sel[2];
    const int tid = threadIdx.x, lane = tid & 63, w = tid >> 6;
    const int b = blockIdx.x;

    // ---- Phase A (redundant in every block, all inputs tiny/L2-hot):
    //      t0, router top-2, shared-LN, per-expert y ----
    if (tid < E) t0s[tid] = cls_token[tid] + pos_embed[tid];
    __syncthreads();
    for (int xx = w; xx < NEXP; xx += 4) {
        const float* rw = router_w + xx * E;
        float s = t0s[lane] * rw[lane] + t0s[64 + lane] * rw[64 + lane];
        s = wave_red64(s);
        if (lane == 0) lgs[xx] = s + router_b[xx];
    }
    __syncthreads();
    if (tid == 0) {  // top-2, jax.lax.top_k tie-break (lower index wins)
        int b0 = 0;
        for (int x = 1; x < NEXP; ++x) if (lgs[x] > lgs[b0]) b0 = x;
        int b1i = -1;
        for (int x = 0; x < NEXP; ++x) { if (x == b0) continue; if (b1i < 0 || lgs[x] > lgs[b1i]) b1i = x; }
        sel[0] = b0; sel[1] = b1i;
    }
    float t0v = (tid < E) ? t0s[tid] : 0.f;
    red[tid] = t0v; __syncthreads();
    for (int s = 128; s > 0; s >>= 1) { if (tid < s) red[tid] += red[tid + s]; __syncthreads(); }
    float m = red[0] * (1.f / E); __syncthreads();
    float d = t0v - m;
    red[tid] = (tid < E) ? d * d : 0.f; __syncthreads();
    for (int s = 128; s > 0; s >>= 1) { if (tid < s) red[tid] += red[tid + s]; __syncthreads(); }
    float xn = d * rsqrtf(red[0] * (1.f / E) + EPS);
    if (tid < E) {
        yS[0][tid] = xn * ln1_g[sel[0] * E + tid] + ln1_b[sel[0] * E + tid];
        yS[1][tid] = xn * ln1_g[sel[1] * E + tid] + ln1_b[sel[1] * E + tid];
    }
    __syncthreads();

    // ---- Phase B: v-proj, one wave per output row (256 waves == 64 blk x 4) ----
    {
        const int r = b * 4 + w, kk = r >> 7, f = r & 127, x = sel[kk];
        const float* row = wv + ((size_t)x * E + f) * E;
        float s = yS[kk][lane] * row[lane] + yS[kk][64 + lane] * row[64 + lane];
        s = wave_red64(s);
        if (lane == 0) ws[WS_A + kk * E + f] = s + bv[x * E + f];
    }
    grid.sync();

    // ---- Phase C: o-proj + residual ----
    {
        const int r = b * 4 + w, kk = r >> 7, f = r & 127, x = sel[kk];
        const float* row = wo + ((size_t)x * E + f) * E;
        float s = ws[WS_A + kk * E + lane] * row[lane] + ws[WS_A + kk * E + 64 + lane] * row[64 + lane];
        s = wave_red64(s);
        if (lane == 0) ws[WS_H + kk * E + f] = t0s[f] + s + bo[x * E + f];
    }
    grid.sync();

    // ---- Phase D: LN2 (redundant, only own expert) + MLP1, 16 outputs/block ----
    const int kkD = b >> 5, xD = sel[kkD];
    float hv = (tid < E) ? ws[WS_H + kkD * E + tid] : 0.f;
    red[tid] = hv; __syncthreads();
    for (int s = 128; s > 0; s >>= 1) { if (tid < s) red[tid] += red[tid + s]; __syncthreads(); }
    float m2 = red[0] * (1.f / E); __syncthreads();
    float d2 = hv - m2;
    red[tid] = (tid < E) ? d2 * d2 : 0.f; __syncthreads();
    for (int s = 128; s > 0; s >>= 1) { if (tid < s) red[tid] += red[tid + s]; __syncthreads(); }
    if (tid < E) hnS[tid] = d2 * rsqrtf(red[0] * (1.f / E) + EPS) * ln2_g[xD * E + tid] + ln2_b[xD * E + tid];
    __syncthreads();
    {
        const int jbase = (b & 31) * 16, i = tid & 15, eg = tid >> 4;
        const float* base = w1 + ((size_t)xD * E + eg * 8) * HDIM + jbase + i;
        float p = 0.f;
        #pragma unroll
        for (int k = 0; k < 8; ++k) p += hnS[eg * 8 + k] * base[(size_t)k * HDIM];
        part[tid] = p;
    }
    __syncthreads();
    if (tid < 16) {
        const int j = (b & 31) * 16 + tid;
        float s = b1[xD * HDIM + j];
        for (int g = 0; g < 16; ++g) s += part[g * 16 + tid];
        ws[WS_MH + kkD * HDIM + j] = 0.5f * s * (1.0f + erff(s * 0.70710678118654752f));
    }
    grid.sync();

    // ---- Phase E: MLP2 partials, blocks 0..15, 64 j's each, coalesced, no atomics ----
    const int kkE = b >> 3, jcE = b & 7;
    if (b < 16 && tid < 64) mhs[tid] = ws[WS_MH + kkE * HDIM + jcE * 64 + tid];
    __syncthreads();
    {
        float s = 0.f;
        if (b < 16) {
            const int xE = sel[kkE], e = tid & 127, jh = tid >> 7;
            const float* base = w2 + (size_t)xE * HDIM * E + (size_t)(jcE * 64 + jh * 32) * E + e;
            #pragma unroll 8
            for (int jj = 0; jj < 32; ++jj) s += mhs[jh * 32 + jj] * base[(size_t)jj * E];
        }
        red[tid] = s;
    }
    __syncthreads();
    if (b < 16 && tid < E) ws[WS_MP + b * E + tid] = red[tid] + red[128 + tid];
    grid.sync();

    // ---- Phase F: MoE combine + final LN (redundant per block) + head + broadcast ----
    float mo = 0.f;
    if (tid < E) {
        float a0 = ws[WS_H + tid]     + b2[sel[0] * E + tid];
        float a1 = ws[WS_H + E + tid] + b2[sel[1] * E + tid];
        #pragma unroll
        for (int jc = 0; jc < 8; ++jc) {
            a0 += ws[WS_MP + jc * E + tid];
            a1 += ws[WS_MP + (8 + jc) * E + tid];
        }
        mo = 0.5f * (a0 + a1);
    }
    red[tid] = mo; __syncthreads();
    for (int s = 128; s > 0; s >>= 1) { if (tid < s) red[tid] += red[tid + s]; __syncthreads(); }
    float m3 = red[0] * (1.f / E); __syncthreads();
    float d3 = mo - m3;
    red[tid] = (tid < E) ? d3 * d3 : 0.f; __syncthreads();
    for (int s = 128; s > 0; s >>= 1) { if (tid < s) red[tid] += red[tid + s]; __syncthreads(); }
    if (tid < E) zS[tid] = d3 * rsqrtf(red[0] * (1.f / E) + EPS) * norm_g[tid] + norm_b[tid];
    __syncthreads();

    // head: wave-per-row, 4 rounds (1000 = 4*250 -> whole blocks valid or not)
    for (int round = 0; round < 4; ++round) {
        const int cbase = round * 256 + b * 4;
        if (cbase < NCLS) {
            const int c = cbase + w;
            const float* row = head_w + (size_t)c * E;
            float s = zS[lane] * row[lane] + zS[64 + lane] * row[64 + lane];
            s = wave_red64(s);
            if (lane == 0) lgq[w] = s + head_b[c];
        }
        __syncthreads();
        if (cbase < NCLS && tid < NB) {
            float4 v = *(const float4*)lgq;   // 4 logits
            *(float4*)(out + (size_t)tid * NCLS + cbase) = v;  // aligned: 1000%4==0
        }
        __syncthreads();
    }
}

extern "C" void kernel_launch(void* const* d_in, const int* in_sizes, int n_in,
                              void* d_out, int out_size, void* d_ws, size_t ws_size,
                              hipStream_t stream) {
    const float* cls_token = (const float*)d_in[3];
    const float* pos_embed = (const float*)d_in[4];
    const float* router_w  = (const float*)d_in[5];
    const float* router_b  = (const float*)d_in[6];
    const float* ln1_g     = (const float*)d_in[7];
    const float* ln1_b     = (const float*)d_in[8];
    const float* wv        = (const float*)d_in[9];
    const float* bv        = (const float*)d_in[10];
    const float* wo        = (const float*)d_in[11];
    const float* bo        = (const float*)d_in[12];
    const float* ln2_g     = (const float*)d_in[13];
    const float* ln2_b     = (const float*)d_in[14];
    const float* w1        = (const float*)d_in[15];
    const float* b1        = (const float*)d_in[16];
    const float* w2        = (const float*)d_in[17];
    const float* b2        = (const float*)d_in[18];
    const float* norm_g    = (const float*)d_in[19];
    const float* norm_b    = (const float*)d_in[20];
    const float* head_w    = (const float*)d_in[21];
    const float* head_b    = (const float*)d_in[22];

    float* ws  = (float*)d_ws;
    float* out = (float*)d_out;

    void* args[] = {
        (void*)&cls_token, (void*)&pos_embed, (void*)&router_w, (void*)&router_b,
        (void*)&ln1_g, (void*)&ln1_b, (void*)&wv, (void*)&bv, (void*)&wo, (void*)&bo,
        (void*)&ln2_g, (void*)&ln2_b, (void*)&w1, (void*)&b1, (void*)&w2, (void*)&b2,
        (void*)&norm_g, (void*)&norm_b, (void*)&head_w, (void*)&head_b,
        (void*)&ws, (void*)&out
    };
    hipLaunchCooperativeKernel((void*)vitmoe_coop, dim3(64), dim3(256), args, 0, stream);
}

// Round 8
// 164.083 us; speedup vs baseline: 1.3619x; 1.3619x over previous
//
#include <hip/hip_runtime.h>
#include <math.h>

#define E     128
#define NEXP  8
#define HDIM  512
#define NCLS  1000
#define NB    128
#define EPS   1e-5f
#define MAGIC 0x5EEDF00D

// ws layout: float ws[0..255] = outs[2][128]; int flags at ((int*)ws)[256..257]

__device__ __forceinline__ float wave_red64(float v) {
    for (int off = 32; off > 0; off >>= 1) v += __shfl_down(v, off, 64);
    return v;
}

// Sums v over tid<128 (others must pass 0). All 1024 threads must call.
__device__ __forceinline__ float block_red128(float v, volatile float* red, int tid) {
    if (tid < 128) red[tid] = v;
    __syncthreads();
    if (tid < 64) {
        float s = red[tid] + red[tid + 64];
        s = wave_red64(s);
        if (tid == 0) red[0] = s;
    }
    __syncthreads();
    float r = red[0];
    __syncthreads();
    return r;
}

// 2 blocks x 1024 threads. Block k owns expert sel[k]; flag-handoff for combine.
__global__ __launch_bounds__(1024) void vitmoe_2blk(
    const float* __restrict__ cls_token, const float* __restrict__ pos_embed,
    const float* __restrict__ router_w,  const float* __restrict__ router_b,
    const float* __restrict__ ln1_g,     const float* __restrict__ ln1_b,
    const float* __restrict__ wv,        const float* __restrict__ bv,
    const float* __restrict__ wo,        const float* __restrict__ bo,
    const float* __restrict__ ln2_g,     const float* __restrict__ ln2_b,
    const float* __restrict__ w1,        const float* __restrict__ b1,
    const float* __restrict__ w2,        const float* __restrict__ b2,
    const float* __restrict__ norm_g,    const float* __restrict__ norm_b,
    const float* __restrict__ head_w,    const float* __restrict__ head_b,
    float* __restrict__ ws,              float* __restrict__ out)
{
    __shared__ float t0s[E], yS[E], aS[E], hS[E], hnS[E], mhS[HDIM], outsS[E], zS[E];
    __shared__ float lgS[512];
    __shared__ float red[1024];
    __shared__ float lgs[NEXP];
    __shared__ int sel[2];
    const int tid = threadIdx.x, lane = tid & 63, wvn = tid >> 6;
    const int k = blockIdx.x;
    int* wsi = (int*)ws;

    // ---- Phase A: t0, router top-2, shared LN, own-expert y (redundant per block) ----
    if (tid < E) t0s[tid] = cls_token[tid] + pos_embed[tid];
    __syncthreads();
    if (wvn < NEXP) {
        const float* rw = router_w + wvn * E;
        float s = t0s[lane] * rw[lane] + t0s[64 + lane] * rw[64 + lane];
        s = wave_red64(s);
        if (lane == 0) lgs[wvn] = s + router_b[wvn];
    }
    __syncthreads();
    if (tid == 0) {  // jax.lax.top_k tie-break: lower index wins
        int b0 = 0;
        for (int x = 1; x < NEXP; ++x) if (lgs[x] > lgs[b0]) b0 = x;
        int b1i = -1;
        for (int x = 0; x < NEXP; ++x) { if (x == b0) continue; if (b1i < 0 || lgs[x] > lgs[b1i]) b1i = x; }
        sel[0] = b0; sel[1] = b1i;
    }
    float t0v = (tid < E) ? t0s[tid] : 0.f;
    float m = block_red128(t0v, red, tid) * (1.f / E);
    float d = (tid < E) ? (t0v - m) : 0.f;
    float var = block_red128(d * d, red, tid) * (1.f / E);
    float xn = d * rsqrtf(var + EPS);
    const int x = sel[k];                       // own expert (sel valid: block_red128 synced)
    if (tid < E) yS[tid] = xn * ln1_g[x * E + tid] + ln1_b[x * E + tid];
    __syncthreads();

    // ---- Phase B: a = wv[x] . y + bv  (8 threads/row, float4) ----
    {
        const int f = tid >> 3, i8 = tid & 7;
        const float4* r4 = (const float4*)(wv + ((size_t)x * E + f) * E + i8 * 16);
        float4 p0 = r4[0], p1 = r4[1], p2 = r4[2], p3 = r4[3];
        const float* yy = yS + i8 * 16;
        float s = p0.x*yy[0]+p0.y*yy[1]+p0.z*yy[2]+p0.w*yy[3]
                + p1.x*yy[4]+p1.y*yy[5]+p1.z*yy[6]+p1.w*yy[7]
                + p2.x*yy[8]+p2.y*yy[9]+p2.z*yy[10]+p2.w*yy[11]
                + p3.x*yy[12]+p3.y*yy[13]+p3.z*yy[14]+p3.w*yy[15];
        s += __shfl_xor(s, 1, 64); s += __shfl_xor(s, 2, 64); s += __shfl_xor(s, 4, 64);
        if (i8 == 0) aS[f] = s + bv[x * E + f];
    }
    __syncthreads();

    // ---- Phase C: h = t0 + wo[x] . a + bo ----
    {
        const int f = tid >> 3, i8 = tid & 7;
        const float4* r4 = (const float4*)(wo + ((size_t)x * E + f) * E + i8 * 16);
        float4 p0 = r4[0], p1 = r4[1], p2 = r4[2], p3 = r4[3];
        const float* aa = aS + i8 * 16;
        float s = p0.x*aa[0]+p0.y*aa[1]+p0.z*aa[2]+p0.w*aa[3]
                + p1.x*aa[4]+p1.y*aa[5]+p1.z*aa[6]+p1.w*aa[7]
                + p2.x*aa[8]+p2.y*aa[9]+p2.z*aa[10]+p2.w*aa[11]
                + p3.x*aa[12]+p3.y*aa[13]+p3.z*aa[14]+p3.w*aa[15];
        s += __shfl_xor(s, 1, 64); s += __shfl_xor(s, 2, 64); s += __shfl_xor(s, 4, 64);
        if (i8 == 0) hS[f] = t0s[f] + s + bo[x * E + f];
    }
    __syncthreads();

    // ---- Phase D: hn = LN2(h) ----
    {
        float hv = (tid < E) ? hS[tid] : 0.f;
        float m2 = block_red128(hv, red, tid) * (1.f / E);
        float d2 = (tid < E) ? (hv - m2) : 0.f;
        float v2 = block_red128(d2 * d2, red, tid) * (1.f / E);
        if (tid < E) hnS[tid] = d2 * rsqrtf(v2 + EPS) * ln2_g[x * E + tid] + ln2_b[x * E + tid];
    }
    __syncthreads();

    // ---- Phase E: mh = gelu(hn . w1 + b1), j split over 512, e split in halves ----
    {
        const int j = tid & 511, half = tid >> 9;
        const float* base = w1 + ((size_t)x * E + half * 64) * HDIM + j;
        const float* hh = hnS + half * 64;
        float s = 0.f;
        #pragma unroll 8
        for (int e = 0; e < 64; ++e) s += hh[e] * base[(size_t)e * HDIM];
        red[tid] = s;
    }
    __syncthreads();
    if (tid < HDIM) {
        float t = red[tid] + red[512 + tid] + b1[x * HDIM + tid];
        mhS[tid] = 0.5f * t * (1.0f + erff(t * 0.70710678118654752f));
    }
    __syncthreads();

    // ---- Phase F: outs = h + mh . w2 + b2 ; publish via device-scope atomics ----
    {
        const int e = tid & 127, jg = tid >> 7;
        const float* base = w2 + ((size_t)x * HDIM + jg * 64) * E + e;
        const float* mm = mhS + jg * 64;
        float s = 0.f;
        #pragma unroll 8
        for (int jj = 0; jj < 64; ++jj) s += mm[jj] * base[(size_t)jj * E];
        red[tid] = s;
    }
    __syncthreads();
    if (tid < E) {
        float o = hS[tid] + b2[x * E + tid];
        #pragma unroll
        for (int g = 0; g < 8; ++g) o += red[g * 128 + tid];
        outsS[tid] = o;
        atomicExch(&ws[k * E + tid], o);
    }
    __threadfence();
    __syncthreads();
    if (tid == 0) atomicExch(&wsi[256 + k], MAGIC);

    // ---- Phase G: wait for peer, combine, final LN (redundant) ----
    if (tid == 0) {
        while (atomicAdd(&wsi[256 + (1 - k)], 0) != MAGIC) __builtin_amdgcn_s_sleep(1);
    }
    __syncthreads();
    float mo = 0.f;
    if (tid < E) {
        float other = atomicAdd(&ws[(1 - k) * E + tid], 0.0f);
        mo = 0.5f * (outsS[tid] + other);
    }
    {
        float m3 = block_red128(mo, red, tid) * (1.f / E);
        float d3 = (tid < E) ? (mo - m3) : 0.f;
        float v3 = block_red128(d3 * d3, red, tid) * (1.f / E);
        if (tid < E) zS[tid] = d3 * rsqrtf(v3 + EPS) * norm_g[tid] + norm_b[tid];
    }
    __syncthreads();

    // ---- Phase H: head rows [k*500, k*500+500), 8 threads/row ----
    for (int round = 0; round < 4; ++round) {
        const int r = round * 128 + (tid >> 3);
        if (r < 500) {
            const int c = k * 500 + r, i8 = tid & 7;
            const float4* r4 = (const float4*)(head_w + (size_t)c * E + i8 * 16);
            float4 p0 = r4[0], p1 = r4[1], p2 = r4[2], p3 = r4[3];
            const float* zz = zS + i8 * 16;
            float s = p0.x*zz[0]+p0.y*zz[1]+p0.z*zz[2]+p0.w*zz[3]
                    + p1.x*zz[4]+p1.y*zz[5]+p1.z*zz[6]+p1.w*zz[7]
                    + p2.x*zz[8]+p2.y*zz[9]+p2.z*zz[10]+p2.w*zz[11]
                    + p3.x*zz[12]+p3.y*zz[13]+p3.z*zz[14]+p3.w*zz[15];
            s += __shfl_xor(s, 1, 64); s += __shfl_xor(s, 2, 64); s += __shfl_xor(s, 4, 64);
            if (i8 == 0) lgS[r] = s + head_b[c];
        }
    }
    __syncthreads();

    // ---- broadcast: 128 rows x 125 float4 per block (cols [k*500, k*500+500)) ----
    for (int idx = tid; idx < NB * 125; idx += 1024) {
        const int bb = idx / 125, q = idx - bb * 125;
        *(float4*)(out + (size_t)bb * NCLS + k * 500 + q * 4) = *(float4*)&lgS[q * 4];
    }
}

extern "C" void kernel_launch(void* const* d_in, const int* in_sizes, int n_in,
                              void* d_out, int out_size, void* d_ws, size_t ws_size,
                              hipStream_t stream) {
    const float* cls_token = (const float*)d_in[3];
    const float* pos_embed = (const float*)d_in[4];
    const float* router_w  = (const float*)d_in[5];
    const float* router_b  = (const float*)d_in[6];
    const float* ln1_g     = (const float*)d_in[7];
    const float* ln1_b     = (const float*)d_in[8];
    const float* wv        = (const float*)d_in[9];
    const float* bv        = (const float*)d_in[10];
    const float* wo        = (const float*)d_in[11];
    const float* bo        = (const float*)d_in[12];
    const float* ln2_g     = (const float*)d_in[13];
    const float* ln2_b     = (const float*)d_in[14];
    const float* w1        = (const float*)d_in[15];
    const float* b1        = (const float*)d_in[16];
    const float* w2        = (const float*)d_in[17];
    const float* b2        = (const float*)d_in[18];
    const float* norm_g    = (const float*)d_in[19];
    const float* norm_b    = (const float*)d_in[20];
    const float* head_w    = (const float*)d_in[21];
    const float* head_b    = (const float*)d_in[22];

    float* ws  = (float*)d_ws;
    float* out = (float*)d_out;

    vitmoe_2blk<<<2, 1024, 0, stream>>>(
        cls_token, pos_embed, router_w, router_b, ln1_g, ln1_b,
        wv, bv, wo, bo, ln2_g, ln2_b, w1, b1, w2, b2,
        norm_g, norm_b, head_w, head_b, ws, out);
}

// Round 10
// 162.702 us; speedup vs baseline: 1.3735x; 1.0085x over previous
//
#include <hip/hip_runtime.h>
#include <math.h>

#define E      128
#define NEXP   8
#define HDIM   512
#define NCLS   1000
#define NB     128
#define EPS    1e-5f
#define MAGIC  0x5EEDF00D
#define MAGIC2 0x7EEDBEEF
#define NBLK   18
#define SLICE  56   // 18*56 = 1008 >= 1000

// ws float layout: [0..255] outs[2][128]; int idx 256,257 expert flags; int idx 258 z-flag;
//                  [272..399] z[128]

__device__ __forceinline__ float wave_red64(float v) {
    for (int off = 32; off > 0; off >>= 1) v += __shfl_down(v, off, 64);
    return v;
}

// Sums v over tid<128 (others must pass 0). All threads must call.
__device__ __forceinline__ float block_red128(float v, volatile float* red, int tid) {
    if (tid < 128) red[tid] = v;
    __syncthreads();
    if (tid < 64) {
        float s = red[tid] + red[tid + 64];
        s = wave_red64(s);
        if (tid == 0) red[0] = s;
    }
    __syncthreads();
    float r = red[0];
    __syncthreads();
    return r;
}

// 18 blocks x 1024 threads: blocks 0-1 = expert chains (flag handoff),
// blocks 2-17 = L2/L3 prefetch helpers + parallel head slices.
__global__ __launch_bounds__(1024) void vitmoe_18blk(
    const float* __restrict__ cls_token, const float* __restrict__ pos_embed,
    const float* __restrict__ router_w,  const float* __restrict__ router_b,
    const float* __restrict__ ln1_g,     const float* __restrict__ ln1_b,
    const float* __restrict__ wv,        const float* __restrict__ bv,
    const float* __restrict__ wo,        const float* __restrict__ bo,
    const float* __restrict__ ln2_g,     const float* __restrict__ ln2_b,
    const float* __restrict__ w1,        const float* __restrict__ b1,
    const float* __restrict__ w2,        const float* __restrict__ b2,
    const float* __restrict__ norm_g,    const float* __restrict__ norm_b,
    const float* __restrict__ head_w,    const float* __restrict__ head_b,
    float* __restrict__ ws,              float* __restrict__ out)
{
    __shared__ float t0s[E], yS[E], aS[E], hS[E], hnS[E], mhS[HDIM], outsS[E], zS[E];
    __shared__ float lgS[64];
    __shared__ float red[1024];
    __shared__ float lgs[NEXP];
    __shared__ int sel[2];
    const int tid = threadIdx.x, lane = tid & 63, wvn = tid >> 6;
    const int b = blockIdx.x;
    int* wsi = (int*)ws;

    // ---- Phase A (all blocks): t0, router logits, top-2 ----
    if (tid < E) t0s[tid] = cls_token[tid] + pos_embed[tid];
    __syncthreads();
    if (wvn < NEXP) {
        const float* rw = router_w + wvn * E;
        float s = t0s[lane] * rw[lane] + t0s[64 + lane] * rw[64 + lane];
        s = wave_red64(s);
        if (lane == 0) lgs[wvn] = s + router_b[wvn];
    }
    __syncthreads();
    if (tid == 0) {  // jax.lax.top_k tie-break: lower index wins
        int b0 = 0;
        for (int x = 1; x < NEXP; ++x) if (lgs[x] > lgs[b0]) b0 = x;
        int b1i = -1;
        for (int x = 0; x < NEXP; ++x) { if (x == b0) continue; if (b1i < 0 || lgs[x] > lgs[b1i]) b1i = x; }
        sel[0] = b0; sel[1] = b1i;
    }
    __syncthreads();

    if (b < 2) {
        // ================= expert chain (block k owns expert sel[k]) =================
        const int k = b;
        float t0v = (tid < E) ? t0s[tid] : 0.f;
        float m = block_red128(t0v, red, tid) * (1.f / E);
        float d = (tid < E) ? (t0v - m) : 0.f;
        float var = block_red128(d * d, red, tid) * (1.f / E);
        float xn = d * rsqrtf(var + EPS);
        const int x = sel[k];
        if (tid < E) yS[tid] = xn * ln1_g[x * E + tid] + ln1_b[x * E + tid];
        __syncthreads();

        // Phase B: a = wv[x] . y + bv  (8 threads/row, float4)
        {
            const int f = tid >> 3, i8 = tid & 7;
            const float4* r4 = (const float4*)(wv + ((size_t)x * E + f) * E + i8 * 16);
            float4 p0 = r4[0], p1 = r4[1], p2 = r4[2], p3 = r4[3];
            const float* yy = yS + i8 * 16;
            float s = p0.x*yy[0]+p0.y*yy[1]+p0.z*yy[2]+p0.w*yy[3]
                    + p1.x*yy[4]+p1.y*yy[5]+p1.z*yy[6]+p1.w*yy[7]
                    + p2.x*yy[8]+p2.y*yy[9]+p2.z*yy[10]+p2.w*yy[11]
                    + p3.x*yy[12]+p3.y*yy[13]+p3.z*yy[14]+p3.w*yy[15];
            s += __shfl_xor(s, 1, 64); s += __shfl_xor(s, 2, 64); s += __shfl_xor(s, 4, 64);
            if (i8 == 0) aS[f] = s + bv[x * E + f];
        }
        __syncthreads();

        // Phase C: h = t0 + wo[x] . a + bo
        {
            const int f = tid >> 3, i8 = tid & 7;
            const float4* r4 = (const float4*)(wo + ((size_t)x * E + f) * E + i8 * 16);
            float4 p0 = r4[0], p1 = r4[1], p2 = r4[2], p3 = r4[3];
            const float* aa = aS + i8 * 16;
            float s = p0.x*aa[0]+p0.y*aa[1]+p0.z*aa[2]+p0.w*aa[3]
                    + p1.x*aa[4]+p1.y*aa[5]+p1.z*aa[6]+p1.w*aa[7]
                    + p2.x*aa[8]+p2.y*aa[9]+p2.z*aa[10]+p2.w*aa[11]
                    + p3.x*aa[12]+p3.y*aa[13]+p3.z*aa[14]+p3.w*aa[15];
            s += __shfl_xor(s, 1, 64); s += __shfl_xor(s, 2, 64); s += __shfl_xor(s, 4, 64);
            if (i8 == 0) hS[f] = t0s[f] + s + bo[x * E + f];
        }
        __syncthreads();

        // Phase D: hn = LN2(h)
        {
            float hv = (tid < E) ? hS[tid] : 0.f;
            float m2 = block_red128(hv, red, tid) * (1.f / E);
            float d2 = (tid < E) ? (hv - m2) : 0.f;
            float v2 = block_red128(d2 * d2, red, tid) * (1.f / E);
            if (tid < E) hnS[tid] = d2 * rsqrtf(v2 + EPS) * ln2_g[x * E + tid] + ln2_b[x * E + tid];
        }
        __syncthreads();

        // Phase E: mh = gelu(hn . w1 + b1)
        {
            const int j = tid & 511, half = tid >> 9;
            const float* base = w1 + ((size_t)x * E + half * 64) * HDIM + j;
            const float* hh = hnS + half * 64;
            float s = 0.f;
            #pragma unroll 8
            for (int e = 0; e < 64; ++e) s += hh[e] * base[(size_t)e * HDIM];
            red[tid] = s;
        }
        __syncthreads();
        if (tid < HDIM) {
            float t = red[tid] + red[512 + tid] + b1[x * HDIM + tid];
            mhS[tid] = 0.5f * t * (1.0f + erff(t * 0.70710678118654752f));
        }
        __syncthreads();

        // Phase F: outs = h + mh . w2 + b2; publish via device-scope atomics
        {
            const int e = tid & 127, jg = tid >> 7;
            const float* base = w2 + ((size_t)x * HDIM + jg * 64) * E + e;
            const float* mm = mhS + jg * 64;
            float s = 0.f;
            #pragma unroll 8
            for (int jj = 0; jj < 64; ++jj) s += mm[jj] * base[(size_t)jj * E];
            red[tid] = s;
        }
        __syncthreads();
        if (tid < E) {
            float o = hS[tid] + b2[x * E + tid];
            #pragma unroll
            for (int g = 0; g < 8; ++g) o += red[g * 128 + tid];
            outsS[tid] = o;
            atomicExch(&ws[k * E + tid], o);
        }
        __threadfence();
        __syncthreads();
        if (tid == 0) atomicExch(&wsi[256 + k], MAGIC);

        // Phase G: wait for peer, combine, final LN
        if (tid == 0) {
            while (atomicAdd(&wsi[256 + (1 - k)], 0) != MAGIC) __builtin_amdgcn_s_sleep(1);
        }
        __syncthreads();
        float mo = 0.f;
        if (tid < E) {
            float other = atomicAdd(&ws[(1 - k) * E + tid], 0.0f);
            mo = 0.5f * (outsS[tid] + other);
        }
        {
            float m3 = block_red128(mo, red, tid) * (1.f / E);
            float d3 = (tid < E) ? (mo - m3) : 0.f;
            float v3 = block_red128(d3 * d3, red, tid) * (1.f / E);
            if (tid < E) zS[tid] = d3 * rsqrtf(v3 + EPS) * norm_g[tid] + norm_b[tid];
        }
        __syncthreads();

        // publish z (block 0 only) so helpers can start the head
        if (k == 0) {
            if (tid < E) atomicExch(&ws[272 + tid], zS[tid]);
            __threadfence();
            __syncthreads();
            if (tid == 0) atomicExch(&wsi[258], MAGIC2);
        }
    } else {
        // ================= helper: prefetch weights into cache, then head =================
        const int x0 = sel[0], x1 = sel[1];
        const int g = (b - 2) * 1024 + tid;        // 0..16383 over 16 helper blocks
        float s = 0.f;
        { const float4* p = (const float4*)(w1 + (size_t)x0 * E * HDIM); float4 v = p[g]; s += v.x + v.y + v.z + v.w; }
        { const float4* p = (const float4*)(w1 + (size_t)x1 * E * HDIM); float4 v = p[g]; s += v.x + v.y + v.z + v.w; }
        { const float4* p = (const float4*)(w2 + (size_t)x0 * HDIM * E); float4 v = p[g]; s += v.x + v.y + v.z + v.w; }
        { const float4* p = (const float4*)(w2 + (size_t)x1 * HDIM * E); float4 v = p[g]; s += v.x + v.y + v.z + v.w; }
        { // wv[x0], wv[x1], wo[x0], wo[x1]: 4 x 4096 float4
          const int a = g >> 13, xi = (g >> 12) & 1, off = g & 4095;
          const float* bp = (a ? wo : wv) + (size_t)sel[xi] * E * E;
          float4 v = ((const float4*)bp)[off]; s += v.x + v.y + v.z + v.w; }
        { // own head slice: rows [b*56, b*56+cnt)
          const int c0 = b * SLICE, cnt = min(SLICE, NCLS - c0);
          const float4* p = (const float4*)(head_w + (size_t)c0 * E);
          for (int idx = tid; idx < cnt * (E / 4); idx += 1024) { float4 v = p[idx]; s += v.x + v.y + v.z + v.w; }
        }
        asm volatile("" :: "v"(s));   // keep loads alive (no DCE)

        // wait for z
        if (tid == 0) {
            while (atomicAdd(&wsi[258], 0) != MAGIC2) __builtin_amdgcn_s_sleep(1);
        }
        __syncthreads();
        if (tid < E) zS[tid] = atomicAdd(&ws[272 + tid], 0.0f);
        __syncthreads();
    }

    // ---- common: head slice b (rows [b*56, b*56+cnt)) + broadcast those columns ----
    const int c0 = b * SLICE, cnt = min(SLICE, NCLS - c0);
    {
        const int r = tid >> 3, i8 = tid & 7;
        if (r < cnt) {
            const int c = c0 + r;
            const float4* r4 = (const float4*)(head_w + (size_t)c * E + i8 * 16);
            float4 p0 = r4[0], p1 = r4[1], p2 = r4[2], p3 = r4[3];
            const float* zz = zS + i8 * 16;
            float s = p0.x*zz[0]+p0.y*zz[1]+p0.z*zz[2]+p0.w*zz[3]
                    + p1.x*zz[4]+p1.y*zz[5]+p1.z*zz[6]+p1.w*zz[7]
                    + p2.x*zz[8]+p2.y*zz[9]+p2.z*zz[10]+p2.w*zz[11]
                    + p3.x*zz[12]+p3.y*zz[13]+p3.z*zz[14]+p3.w*zz[15];
            s += __shfl_xor(s, 1, 64); s += __shfl_xor(s, 2, 64); s += __shfl_xor(s, 4, 64);
            if (i8 == 0) lgS[r] = s + head_b[c];
        }
    }
    __syncthreads();
    {
        const int nq = cnt >> 2;   // float4s per batch row (14 or 12) — c0 % 8 == 0 so aligned
        for (int idx = tid; idx < NB * nq; idx += 1024) {
            const int bb = idx / nq, q = idx - bb * nq;
            *(float4*)(out + (size_t)bb * NCLS + c0 + q * 4) = *(float4*)&lgS[q * 4];
        }
    }
}

extern "C" void kernel_launch(void* const* d_in, const int* in_sizes, int n_in,
                              void* d_out, int out_size, void* d_ws, size_t ws_size,
                              hipStream_t stream) {
    const float* cls_token = (const float*)d_in[3];
    const float* pos_embed = (const float*)d_in[4];
    const float* router_w  = (const float*)d_in[5];
    const float* router_b  = (const float*)d_in[6];
    const float* ln1_g     = (const float*)d_in[7];
    const float* ln1_b     = (const float*)d_in[8];
    const float* wv        = (const float*)d_in[9];
    const float* bv        = (const float*)d_in[10];
    const float* wo        = (const float*)d_in[11];
    const float* bo        = (const float*)d_in[12];
    const float* ln2_g     = (const float*)d_in[13];
    const float* ln2_b     = (const float*)d_in[14];
    const float* w1        = (const float*)d_in[15];
    const float* b1        = (const float*)d_in[16];
    const float* w2        = (const float*)d_in[17];
    const float* b2        = (const float*)d_in[18];
    const float* norm_g    = (const float*)d_in[19];
    const float* norm_b    = (const float*)d_in[20];
    const float* head_w    = (const float*)d_in[21];
    const float* head_b    = (const float*)d_in[22];

    float* ws  = (float*)d_ws;
    float* out = (float*)d_out;

    vitmoe_18blk<<<NBLK, 1024, 0, stream>>>(
        cls_token, pos_embed, router_w, router_b, ln1_g, ln1_b,
        wv, bv, wo, bo, ln2_g, ln2_b, w1, b1, w2, b2,
        norm_g, norm_b, head_w, head_b, ws, out);
}